// Round 4
// baseline (6036.637 us; speedup 1.0000x reference)
//
#include <hip/hip_runtime.h>
#include <hip/hip_bf16.h>
#include <stdint.h>

#define T_STEPS 512
#define BATCH   64
#define DIN     512
#define HID     1024
#define KDIM    1536        // HID + DIN (concat order: h then x)
#define NBLK    128         // persistent blocks (1 per CU, <=256 CUs)
#define HPB     8           // hidden cols per block
#define GCPB    32          // gate cols per block = 4 gates * HPB
#define KGRPS   192         // KDIM / 8
#define XKG     64          // x-part kgrps (DIN/8)

typedef __bf16 bf16x8 __attribute__((ext_vector_type(8)));
typedef float  f32x4  __attribute__((ext_vector_type(4)));
typedef unsigned short ushort_t;
typedef unsigned long long u64_t;

__device__ __forceinline__ ushort_t f2bf(float f) {
    union { float f; unsigned u; } v; v.f = f;
    unsigned u = v.u;
    u += 0x7FFFu + ((u >> 16) & 1u);   // RNE
    return (ushort_t)(u >> 16);
}

__device__ __forceinline__ float fast_sig(float x) {
    return __builtin_amdgcn_rcpf(1.0f + __expf(-x));
}
__device__ __forceinline__ float fast_tanh(float x) {
    float e = __expf(2.0f * x);
    return 1.0f - 2.0f * __builtin_amdgcn_rcpf(e + 1.0f);
}

// ---------------- prep kernel 1: x fp32 -> bf16 ----------------
__global__ void cvt_x(const float* __restrict__ x, ushort_t* __restrict__ xb, int n8) {
    int i = blockIdx.x * blockDim.x + threadIdx.x;
    if (i >= n8) return;
    float4 v0 = ((const float4*)x)[2 * i];
    float4 v1 = ((const float4*)x)[2 * i + 1];
    uint4 o;
    o.x = (unsigned)f2bf(v0.x) | ((unsigned)f2bf(v0.y) << 16);
    o.y = (unsigned)f2bf(v0.z) | ((unsigned)f2bf(v0.w) << 16);
    o.z = (unsigned)f2bf(v1.x) | ((unsigned)f2bf(v1.y) << 16);
    o.w = (unsigned)f2bf(v1.z) | ((unsigned)f2bf(v1.w) << 16);
    ((uint4*)xb)[i] = o;
}

// ---------------- prep kernel 2: transpose W into per-block chunk-major bf16 ----------------
// wt[blk][kgrp][n][8] bf16, blk=hiddencol/8, n = gate*8 + hiddencol%8, k = kgrp*8+j
__global__ void xpose_w(const float* __restrict__ Wi, const float* __restrict__ Wf,
                        const float* __restrict__ Wo, const float* __restrict__ Wg,
                        ushort_t* __restrict__ wt) {
    __shared__ float tile[64][65];
    int kt = blockIdx.x, nt = blockIdx.y, g = blockIdx.z;
    const float* W = (g == 0) ? Wi : (g == 1) ? Wf : (g == 2) ? Wo : Wg;
    int k0 = kt * 64, n0 = nt * 64;
    int c = threadIdx.x & 63, r0 = threadIdx.x >> 6;
#pragma unroll
    for (int i = 0; i < 16; ++i) {
        int r = r0 + i * 4;
        tile[r][c] = W[(size_t)(k0 + r) * HID + n0 + c];
    }
    __syncthreads();
#pragma unroll
    for (int p = 0; p < 2; ++p) {
        int q = threadIdx.x + p * 256;
        int n_inner = q & 7;
        int kgl = (q >> 3) & 7;
        int bl = q >> 6;
        int n = n0 + bl * 8 + n_inner;
        int blk = n >> 3;
        int nn = g * 8 + (n & 7);
        int kgrp = (k0 >> 3) + kgl;
        __align__(16) ushort_t tmp[8];
#pragma unroll
        for (int j = 0; j < 8; ++j) tmp[j] = f2bf(tile[kgl * 8 + j][bl * 8 + n_inner]);
        *(uint4*)(wt + ((((size_t)blk * KGRPS + kgrp) * GCPB + nn) << 3)) = *(const uint4*)tmp;
    }
}

// ---------------- persistent LSTM kernel (wave-specialized) ----------------
// Waves 0-1: sync + h-GEMM (K chunks 0..31) + pointwise + h-store + flag.
//            NEVER touch x or out -> their vmcnt chain holds ONLY protocol ops.
// Waves 2-3: x-GEMM (K chunks 32..47, W from LDS, x prefetched 1 step ahead)
//            + fp32 out writes (via hvbuf LDS handoff). All off critical path.
__global__ __launch_bounds__(256, 1) void lstm_persist(
    const ushort_t* __restrict__ xbf,   // [T][B][DIN] bf16
    const ushort_t* __restrict__ wt,    // [NBLK][KGRPS][GCPB][8] bf16
    const float* __restrict__ h0, const float* __restrict__ C0,
    const float* __restrict__ b_i, const float* __restrict__ b_f,
    const float* __restrict__ b_o, const float* __restrict__ b_g,
    ushort_t* __restrict__ hbuf,        // [2][B][HID] bf16 double buffer
    unsigned* __restrict__ flags,       // [NBLK] at 32-uint (128B) spacing
    float* __restrict__ out)            // hs [T][B][HID] then C [B][HID]
{
    __shared__ __align__(16) ushort_t Wlx[XKG][GCPB][8];   // 32 KB: x-part W for waves 2-3
    __shared__ float gbuf[4][BATCH][GCPB + 2];             // ~34.8 KB partials
    __shared__ float Cl[BATCH][HPB + 1];
    __shared__ float hvbuf[BATCH][HPB];                    // fp32 h handoff to out-waves
    __shared__ float cvbuf[BATCH][HPB];
    __shared__ float biasl[GCPB];

    const int tid  = threadIdx.x;
    const int blk  = blockIdx.x;
    const int wave = tid >> 6;
    const int lane = tid & 63;
    const int j0   = blk * HPB;
    const int m_lane = lane & 15;
    const int quad   = lane >> 4;
    const int koff   = quad * 8;

    const ushort_t* wblk = wt + (size_t)blk * KGRPS * GCPB * 8;

    // h-part W fragments -> registers (waves 0-1 only; 16 chunks x 2 coltiles)
    bf16x8 wbh[16][2];
    if (wave < 2) {
#pragma unroll
        for (int cc = 0; cc < 16; ++cc) {
            const int kgrp = (wave * 16 + cc) * 4 + quad;
            wbh[cc][0] = *(const bf16x8*)(wblk + ((size_t)kgrp * GCPB + m_lane) * 8);
            wbh[cc][1] = *(const bf16x8*)(wblk + ((size_t)kgrp * GCPB + 16 + m_lane) * 8);
        }
    }
    // x-part W -> LDS (kgrps 128..191), staged by all threads
    {
        const uint4* src = (const uint4*)(wblk + (size_t)128 * GCPB * 8);
        uint4* dst = (uint4*)(&Wlx[0][0][0]);
        for (int i = tid; i < XKG * GCPB; i += 256) dst[i] = src[i];
    }

    if (tid < GCPB) {
        int g = tid >> 3, j = tid & 7;
        const float* bp = (g == 0) ? b_i : (g == 1) ? b_f : (g == 2) ? b_o : b_g;
        biasl[tid] = bp[j0 + j];
    }
    if (tid < 128) {
        int b = tid >> 1, jh = (tid & 1) * 4;
#pragma unroll
        for (int jj = 0; jj < 4; ++jj)
            Cl[b][jh + jj] = C0[b * HID + j0 + jh + jj];
        u64_t pk = 0;
#pragma unroll
        for (int jj = 0; jj < 4; ++jj)
            pk |= (u64_t)f2bf(h0[b * HID + j0 + jh + jj]) << (16 * jj);
        __hip_atomic_store((u64_t*)(hbuf + b * HID + j0 + jh), pk,
                           __ATOMIC_RELAXED, __HIP_MEMORY_SCOPE_AGENT);
    }
    asm volatile("s_waitcnt vmcnt(0)" ::: "memory");
    __syncthreads();
    if (tid == 0)
        __hip_atomic_store(&flags[blk * 32], 1u, __ATOMIC_RELAXED, __HIP_MEMORY_SCOPE_AGENT);

    // prologue: x(t=0) prefetch for waves 2-3
    bf16x8 ax[8][4];
    if (wave >= 2) {
#pragma unroll
        for (int cc = 0; cc < 8; ++cc) {
            const ushort_t* ap = xbf + ((wave - 2) * 8 + cc) * 32 + koff;
#pragma unroll
            for (int rt = 0; rt < 4; ++rt)
                ax[cc][rt] = *(const bf16x8*)(ap + (size_t)(rt * 16 + m_lane) * DIN);
        }
    }

    int pb = 0;
    for (int t = 0; t < T_STEPS; ++t) {
        if (wave < 2) {
            // =========== sync/h waves ===========
            // spin: 128 threads (waves 0-1) each poll one flag.
            // Nothing else outstanding in these waves -> poll waits are clean.
            while (__hip_atomic_load(&flags[tid * 32], __ATOMIC_RELAXED,
                                     __HIP_MEMORY_SCOPE_AGENT) < (unsigned)(t + 1))
                __builtin_amdgcn_s_sleep(1);
            __syncthreads();                                   // S
            __builtin_amdgcn_fence(__ATOMIC_ACQUIRE, "agent"); // drain is free here
            __builtin_amdgcn_sched_barrier(0);

            const ushort_t* hsrc = hbuf + pb * BATCH * HID;
            const int hc0 = wave * 16;

            f32x4 acc[4][2];
#pragma unroll
            for (int rt = 0; rt < 4; ++rt) {
                acc[rt][0] = (f32x4){0.f, 0.f, 0.f, 0.f};
                acc[rt][1] = (f32x4){0.f, 0.f, 0.f, 0.f};
            }

            // 4 batches of 4 chunks, 2-batch lookahead (<=128 VGPR of A-frags live)
            bf16x8 a0[4][4], a1[4][4], a2[4][4], a3[4][4];
#define LOADB(dst, c0)                                                        \
            _Pragma("unroll") for (int q = 0; q < 4; ++q) {                   \
                const ushort_t* ap = hsrc + (size_t)(hc0 + (c0) + q) * 32 + koff; \
                _Pragma("unroll") for (int rt = 0; rt < 4; ++rt)              \
                    dst[q][rt] = *(const bf16x8*)(ap + (size_t)(rt * 16 + m_lane) * HID); \
            }
#define MFMAB(src, c0)                                                        \
            _Pragma("unroll") for (int q = 0; q < 4; ++q) {                   \
                _Pragma("unroll") for (int rt = 0; rt < 4; ++rt) {            \
                    acc[rt][0] = __builtin_amdgcn_mfma_f32_16x16x32_bf16(     \
                        src[q][rt], wbh[(c0) + q][0], acc[rt][0], 0, 0, 0);   \
                    acc[rt][1] = __builtin_amdgcn_mfma_f32_16x16x32_bf16(     \
                        src[q][rt], wbh[(c0) + q][1], acc[rt][1], 0, 0, 0);   \
                }                                                             \
            }
            LOADB(a0, 0)
            LOADB(a1, 4)
            MFMAB(a0, 0)
            LOADB(a2, 8)
            MFMAB(a1, 4)
            LOADB(a3, 12)
            MFMAB(a2, 8)
            MFMAB(a3, 12)
#undef LOADB
#undef MFMAB

            // K-partials: D[row=(lane>>4)*4+r][col=lane&15]
#pragma unroll
            for (int rt = 0; rt < 4; ++rt)
#pragma unroll
                for (int ct = 0; ct < 2; ++ct)
#pragma unroll
                    for (int r = 0; r < 4; ++r)
                        gbuf[wave][rt * 16 + quad * 4 + r][ct * 16 + m_lane] = acc[rt][ct][r];
            __syncthreads();                                   // A

            // pointwise: all 128 threads of waves 0-1; (batch row b, 4 cols)
            float hv[4], cv[4];
            const int b = tid >> 1, jh = (tid & 1) * 4;
#pragma unroll
            for (int jj = 0; jj < 4; ++jj) {
                int j = jh + jj;
                float pre[4];
#pragma unroll
                for (int g = 0; g < 4; ++g) {
                    int col = g * 8 + j;
                    pre[g] = biasl[col] + gbuf[0][b][col] + gbuf[1][b][col]
                                        + gbuf[2][b][col] + gbuf[3][b][col];
                }
                float ig = fast_sig(pre[0]);
                float fg = fast_sig(pre[1]);
                float og = fast_sig(pre[2]);
                float gg = fast_tanh(pre[3]);
                float c_new = fg * Cl[b][jh + jj] + ig * gg;
                Cl[b][jh + jj] = c_new;
                cv[jj] = c_new;
                hv[jj] = og * fast_tanh(c_new);
            }
            // fp32 handoff to out-waves (LDS), then bf16 h broadcast store
            {
                float4 o4; o4.x = hv[0]; o4.y = hv[1]; o4.z = hv[2]; o4.w = hv[3];
                *(float4*)(&hvbuf[b][jh]) = o4;
                if (t == T_STEPS - 1) {
                    float4 c4; c4.x = cv[0]; c4.y = cv[1]; c4.z = cv[2]; c4.w = cv[3];
                    *(float4*)(&cvbuf[b][jh]) = c4;
                }
            }
            u64_t pk = (u64_t)f2bf(hv[0]) | ((u64_t)f2bf(hv[1]) << 16)
                     | ((u64_t)f2bf(hv[2]) << 32) | ((u64_t)f2bf(hv[3]) << 48);
            __hip_atomic_store((u64_t*)(hbuf + (1 - pb) * BATCH * HID + b * HID + j0 + jh),
                               pk, __ATOMIC_RELAXED, __HIP_MEMORY_SCOPE_AGENT);
            asm volatile("s_waitcnt vmcnt(0)" ::: "memory");   // h stores ONLY
            __syncthreads();                                   // B
            if (tid == 0)
                __hip_atomic_store(&flags[blk * 32], (unsigned)(t + 2), __ATOMIC_RELAXED,
                                   __HIP_MEMORY_SCOPE_AGENT);
        } else {
            // =========== x/out waves ===========
            f32x4 acc[4][2];
#pragma unroll
            for (int rt = 0; rt < 4; ++rt) {
                acc[rt][0] = (f32x4){0.f, 0.f, 0.f, 0.f};
                acc[rt][1] = (f32x4){0.f, 0.f, 0.f, 0.f};
            }
            // x MFMAs for step t (ax prefetched a full step ago; W from LDS)
#pragma unroll
            for (int cc = 0; cc < 8; ++cc) {
                const int kgx = ((wave - 2) * 8 + cc) * 4 + quad;
                bf16x8 b0 = *(const bf16x8*)(&Wlx[kgx][m_lane][0]);
                bf16x8 b1 = *(const bf16x8*)(&Wlx[kgx][16 + m_lane][0]);
#pragma unroll
                for (int rt = 0; rt < 4; ++rt) {
                    acc[rt][0] = __builtin_amdgcn_mfma_f32_16x16x32_bf16(ax[cc][rt], b0, acc[rt][0], 0, 0, 0);
                    acc[rt][1] = __builtin_amdgcn_mfma_f32_16x16x32_bf16(ax[cc][rt], b1, acc[rt][1], 0, 0, 0);
                }
            }
#pragma unroll
            for (int rt = 0; rt < 4; ++rt)
#pragma unroll
                for (int ct = 0; ct < 2; ++ct)
#pragma unroll
                    for (int r = 0; r < 4; ++r)
                        gbuf[wave][rt * 16 + quad * 4 + r][ct * 16 + m_lane] = acc[rt][ct][r];
            __syncthreads();                                   // S

            // prefetch x(t+1): lands during pointwise + next spin (~several us)
            if (t + 1 < T_STEPS) {
                const ushort_t* xsrc = xbf + (size_t)(t + 1) * BATCH * DIN;
#pragma unroll
                for (int cc = 0; cc < 8; ++cc) {
                    const ushort_t* ap = xsrc + ((wave - 2) * 8 + cc) * 32 + koff;
#pragma unroll
                    for (int rt = 0; rt < 4; ++rt)
                        ax[cc][rt] = *(const bf16x8*)(ap + (size_t)(rt * 16 + m_lane) * DIN);
                }
            }
            __syncthreads();                                   // A
            __syncthreads();                                   // B

            // fp32 out from LDS handoff — fully off the sync-critical path
            const int tid2 = tid - 128;
            const int b = tid2 >> 1, jh = (tid2 & 1) * 4;
            float4 o4 = *(const float4*)(&hvbuf[b][jh]);
            *(float4*)(out + (size_t)t * BATCH * HID + b * HID + j0 + jh) = o4;
            if (t == T_STEPS - 1) {
                float4 c4 = *(const float4*)(&cvbuf[b][jh]);
                *(float4*)(out + (size_t)T_STEPS * BATCH * HID + b * HID + j0 + jh) = c4;
            }
        }
        pb ^= 1;
    }
}

extern "C" void kernel_launch(void* const* d_in, const int* in_sizes, int n_in,
                              void* d_out, int out_size, void* d_ws, size_t ws_size,
                              hipStream_t stream) {
    (void)in_sizes; (void)n_in; (void)out_size; (void)ws_size;
    const float* x  = (const float*)d_in[0];
    const float* h0 = (const float*)d_in[1];
    const float* C0 = (const float*)d_in[2];
    const float* Wi = (const float*)d_in[3];
    const float* bi = (const float*)d_in[4];
    const float* Wf = (const float*)d_in[5];
    const float* bf = (const float*)d_in[6];
    const float* Wo = (const float*)d_in[7];
    const float* bo = (const float*)d_in[8];
    const float* Wg = (const float*)d_in[9];
    const float* bg = (const float*)d_in[10];
    float* out = (float*)d_out;

    char* ws = (char*)d_ws;
    unsigned*  flags = (unsigned*)ws;                                  // 16 KB (128 x 128B)
    ushort_t*  hbuf  = (ushort_t*)(ws + 16384);                        // 256 KB
    ushort_t*  xb    = (ushort_t*)(ws + 16384 + 262144);               // 32 MB
    ushort_t*  wt    = (ushort_t*)(ws + 16384 + 262144 + 33554432);    // 12 MB

    hipMemsetAsync(flags, 0, 16384, stream);
    cvt_x<<<8192, 256, 0, stream>>>(x, xb, (T_STEPS * BATCH * DIN) / 8);
    xpose_w<<<dim3(24, 16, 4), 256, 0, stream>>>(Wi, Wf, Wo, Wg, wt);
    lstm_persist<<<NBLK, 256, 0, stream>>>(xb, wt, h0, C0, bi, bf, bo, bg, hbuf, flags, out);
}

// Round 5
// 4790.109 us; speedup vs baseline: 1.2602x; 1.2602x over previous
//
#include <hip/hip_runtime.h>
#include <hip/hip_bf16.h>
#include <stdint.h>

#define T_STEPS 512
#define BATCH   64
#define DIN     512
#define HID     1024
#define KDIM    1536        // HID + DIN (concat order: h then x)
#define NBLK    64          // persistent blocks (halved: less broadcast + sync degree)
#define HPB     16          // hidden cols per block
#define GCPB    64          // gate cols per block = 4 gates * HPB
#define KGRPS   192         // KDIM / 8
#define XKG     64          // x-part kgrps (DIN/8)

typedef __bf16 bf16x8 __attribute__((ext_vector_type(8)));
typedef float  f32x4  __attribute__((ext_vector_type(4)));
typedef unsigned short ushort_t;
typedef unsigned long long u64_t;

__device__ __forceinline__ ushort_t f2bf(float f) {
    union { float f; unsigned u; } v; v.f = f;
    unsigned u = v.u;
    u += 0x7FFFu + ((u >> 16) & 1u);   // RNE
    return (ushort_t)(u >> 16);
}

__device__ __forceinline__ float fast_sig(float x) {
    return __builtin_amdgcn_rcpf(1.0f + __expf(-x));
}
__device__ __forceinline__ float fast_tanh(float x) {
    float e = __expf(2.0f * x);
    return 1.0f - 2.0f * __builtin_amdgcn_rcpf(e + 1.0f);
}

// ---------------- prep kernel 1: x fp32 -> bf16 ----------------
__global__ void cvt_x(const float* __restrict__ x, ushort_t* __restrict__ xb, int n8) {
    int i = blockIdx.x * blockDim.x + threadIdx.x;
    if (i >= n8) return;
    float4 v0 = ((const float4*)x)[2 * i];
    float4 v1 = ((const float4*)x)[2 * i + 1];
    uint4 o;
    o.x = (unsigned)f2bf(v0.x) | ((unsigned)f2bf(v0.y) << 16);
    o.y = (unsigned)f2bf(v0.z) | ((unsigned)f2bf(v0.w) << 16);
    o.z = (unsigned)f2bf(v1.x) | ((unsigned)f2bf(v1.y) << 16);
    o.w = (unsigned)f2bf(v1.z) | ((unsigned)f2bf(v1.w) << 16);
    ((uint4*)xb)[i] = o;
}

// ---------------- prep kernel 2: transpose W into per-block chunk-major bf16 ----------------
// wt[blk][kgrp][nn][8] bf16, blk = hidcol/HPB, nn = gate*HPB + hidcol%HPB, k = kgrp*8+j
__global__ void xpose_w(const float* __restrict__ Wi, const float* __restrict__ Wf,
                        const float* __restrict__ Wo, const float* __restrict__ Wg,
                        ushort_t* __restrict__ wt) {
    __shared__ float tile[64][65];
    int kt = blockIdx.x, nt = blockIdx.y, g = blockIdx.z;
    const float* W = (g == 0) ? Wi : (g == 1) ? Wf : (g == 2) ? Wo : Wg;
    int k0 = kt * 64, n0 = nt * 64;
    int c = threadIdx.x & 63, r0 = threadIdx.x >> 6;
#pragma unroll
    for (int i = 0; i < 16; ++i) {
        int r = r0 + i * 4;
        tile[r][c] = W[(size_t)(k0 + r) * HID + n0 + c];
    }
    __syncthreads();
#pragma unroll
    for (int p = 0; p < 2; ++p) {
        int q = threadIdx.x + p * 256;
        int n_inner = q & 7;
        int kgl = (q >> 3) & 7;
        int bl = q >> 6;
        int n = n0 + bl * 8 + n_inner;
        int blk = n >> 4;                 // HPB = 16
        int nn = g * HPB + (n & 15);
        int kgrp = (k0 >> 3) + kgl;
        __align__(16) ushort_t tmp[8];
#pragma unroll
        for (int j = 0; j < 8; ++j) tmp[j] = f2bf(tile[kgl * 8 + j][bl * 8 + n_inner]);
        *(uint4*)(wt + ((((size_t)blk * KGRPS + kgrp) * GCPB + nn) << 3)) = *(const uint4*)tmp;
    }
}

// ---------------- persistent LSTM kernel ----------------
// 64 blocks x 256 thr. Each block owns 16 hidden cols (64 gate cols).
// 4-wave K-split (proven r1 structure). h-W resident in VGPRs (128/lane),
// x-W resident in LDS (64KB). Per-step: x loads -> spin -> fence ->
// h loads -> x MFMAs (cover h window) -> h MFMAs -> gbuf -> pointwise ->
// h store/flag -> out.
__global__ __launch_bounds__(256, 1) void lstm_persist(
    const ushort_t* __restrict__ xbf,   // [T][B][DIN] bf16
    const ushort_t* __restrict__ wt,    // [NBLK][KGRPS][GCPB][8] bf16
    const float* __restrict__ h0, const float* __restrict__ C0,
    const float* __restrict__ b_i, const float* __restrict__ b_f,
    const float* __restrict__ b_o, const float* __restrict__ b_g,
    ushort_t* __restrict__ hbuf,        // [2][B][HID] bf16 double buffer
    unsigned* __restrict__ flags,       // [NBLK] at 32-uint (128B) spacing
    float* __restrict__ out)            // hs [T][B][HID] then C [B][HID]
{
    __shared__ __align__(16) ushort_t Wlx[XKG][GCPB][8];   // 64 KB x-part W
    __shared__ float gbuf[4][BATCH][GCPB + 2];             // 67.6 KB partials
    __shared__ float Cl[BATCH][HPB + 1];
    __shared__ float biasl[GCPB];

    const int tid  = threadIdx.x;
    const int blk  = blockIdx.x;
    const int wave = tid >> 6;
    const int lane = tid & 63;
    const int j0   = blk * HPB;
    const int m_lane = lane & 15;
    const int quad   = lane >> 4;
    const int koff   = quad * 8;

    const ushort_t* wblk = wt + (size_t)blk * KGRPS * GCPB * 8;

    // h-part W fragments -> registers: 8 chunks x 4 coltiles per wave (128 VGPR)
    bf16x8 wbh[8][4];
#pragma unroll
    for (int cc = 0; cc < 8; ++cc) {
        const int kgrp = (wave * 8 + cc) * 4 + quad;
#pragma unroll
        for (int ct = 0; ct < 4; ++ct)
            wbh[cc][ct] = *(const bf16x8*)(wblk + ((size_t)kgrp * GCPB + ct * 16 + m_lane) * 8);
    }
    // x-part W (kgrps 128..191) -> LDS
    {
        const uint4* src = (const uint4*)(wblk + (size_t)128 * GCPB * 8);
        uint4* dst = (uint4*)(&Wlx[0][0][0]);
        for (int i = tid; i < XKG * GCPB; i += 256) dst[i] = src[i];
    }

    if (tid < GCPB) {
        int g = tid >> 4, j = tid & 15;
        const float* bp = (g == 0) ? b_i : (g == 1) ? b_f : (g == 2) ? b_o : b_g;
        biasl[tid] = bp[j0 + j];
    }
    {
        int b = tid >> 2, jh = (tid & 3) * 4;
#pragma unroll
        for (int jj = 0; jj < 4; ++jj)
            Cl[b][jh + jj] = C0[b * HID + j0 + jh + jj];
        u64_t pk = 0;
#pragma unroll
        for (int jj = 0; jj < 4; ++jj)
            pk |= (u64_t)f2bf(h0[b * HID + j0 + jh + jj]) << (16 * jj);
        __hip_atomic_store((u64_t*)(hbuf + b * HID + j0 + jh), pk,
                           __ATOMIC_RELAXED, __HIP_MEMORY_SCOPE_AGENT);
    }
    asm volatile("s_waitcnt vmcnt(0)" ::: "memory");
    __syncthreads();
    if (tid == 0)
        __hip_atomic_store(&flags[blk * 32], 1u, __ATOMIC_RELAXED, __HIP_MEMORY_SCOPE_AGENT);

    int pb = 0;
    for (int t = 0; t < T_STEPS; ++t) {
        const ushort_t* xsrc = xbf + (size_t)t * BATCH * DIN;
        const ushort_t* hsrc = hbuf + pb * BATCH * HID;

        f32x4 acc[4][4];
#pragma unroll
        for (int rt = 0; rt < 4; ++rt)
#pragma unroll
            for (int ct = 0; ct < 4; ++ct)
                acc[rt][ct] = (f32x4){0.f, 0.f, 0.f, 0.f};

        // ---- x(t) loads before the spin: complete for free while waiting ----
        bf16x8 ax[4][4];
#pragma unroll
        for (int cc = 0; cc < 4; ++cc) {
            const ushort_t* ap = xsrc + (wave * 4 + cc) * 32 + koff;
#pragma unroll
            for (int rt = 0; rt < 4; ++rt)
                ax[cc][rt] = *(const bf16x8*)(ap + (size_t)(rt * 16 + m_lane) * DIN);
        }
        __builtin_amdgcn_sched_barrier(0);

        // ---- wait for all 64 blocks' h(t): single-wave poll ----
        if (tid < NBLK) {
            while (__hip_atomic_load(&flags[tid * 32], __ATOMIC_RELAXED,
                                     __HIP_MEMORY_SCOPE_AGENT) < (unsigned)(t + 1))
                __builtin_amdgcn_s_sleep(1);
        }
        __syncthreads();
        __builtin_amdgcn_fence(__ATOMIC_ACQUIRE, "agent");   // buffer_inv (no wbl2)
        __builtin_amdgcn_sched_barrier(0);

        // ---- issue all h loads (32 x 16B per lane) ----
        bf16x8 ah[8][4];
#pragma unroll
        for (int cc = 0; cc < 8; ++cc) {
            const ushort_t* ap = hsrc + (wave * 8 + cc) * 32 + koff;
#pragma unroll
            for (int rt = 0; rt < 4; ++rt)
                ah[cc][rt] = *(const bf16x8*)(ap + (size_t)(rt * 16 + m_lane) * HID);
        }
        __builtin_amdgcn_sched_barrier(0);

        // ---- x MFMAs (W from LDS): cover the h-load latency window ----
#pragma unroll
        for (int cc = 0; cc < 4; ++cc) {
            const int kgx = (wave * 4 + cc) * 4 + quad;
            bf16x8 bb[4];
#pragma unroll
            for (int ct = 0; ct < 4; ++ct)
                bb[ct] = *(const bf16x8*)(&Wlx[kgx][ct * 16 + m_lane][0]);
#pragma unroll
            for (int rt = 0; rt < 4; ++rt)
#pragma unroll
                for (int ct = 0; ct < 4; ++ct)
                    acc[rt][ct] = __builtin_amdgcn_mfma_f32_16x16x32_bf16(ax[cc][rt], bb[ct], acc[rt][ct], 0, 0, 0);
        }

        // ---- h MFMAs: A from just-landed regs, B resident in VGPRs ----
#pragma unroll
        for (int cc = 0; cc < 8; ++cc)
#pragma unroll
            for (int rt = 0; rt < 4; ++rt)
#pragma unroll
                for (int ct = 0; ct < 4; ++ct)
                    acc[rt][ct] = __builtin_amdgcn_mfma_f32_16x16x32_bf16(ah[cc][rt], wbh[cc][ct], acc[rt][ct], 0, 0, 0);

        // K-partials: D[row=(lane>>4)*4+r][col=lane&15]
#pragma unroll
        for (int rt = 0; rt < 4; ++rt)
#pragma unroll
            for (int ct = 0; ct < 4; ++ct)
#pragma unroll
                for (int r = 0; r < 4; ++r)
                    gbuf[wave][rt * 16 + quad * 4 + r][ct * 16 + m_lane] = acc[rt][ct][r];
        __syncthreads();

        // pointwise: 256 threads, each owns (batch row b, 4 of 16 cols)
        float hv[4], cv[4];
        const int b = tid >> 2, jh = (tid & 3) * 4;
#pragma unroll
        for (int jj = 0; jj < 4; ++jj) {
            int j = jh + jj;
            float pre[4];
#pragma unroll
            for (int g = 0; g < 4; ++g) {
                int col = g * HPB + j;
                pre[g] = biasl[col] + gbuf[0][b][col] + gbuf[1][b][col]
                                    + gbuf[2][b][col] + gbuf[3][b][col];
            }
            float ig = fast_sig(pre[0]);
            float fg = fast_sig(pre[1]);
            float og = fast_sig(pre[2]);
            float gg = fast_tanh(pre[3]);
            float c_new = fg * Cl[b][jh + jj] + ig * gg;
            Cl[b][jh + jj] = c_new;
            cv[jj] = c_new;
            hv[jj] = og * fast_tanh(c_new);
        }
        u64_t pk = (u64_t)f2bf(hv[0]) | ((u64_t)f2bf(hv[1]) << 16)
                 | ((u64_t)f2bf(hv[2]) << 32) | ((u64_t)f2bf(hv[3]) << 48);
        __hip_atomic_store((u64_t*)(hbuf + (1 - pb) * BATCH * HID + b * HID + j0 + jh),
                           pk, __ATOMIC_RELAXED, __HIP_MEMORY_SCOPE_AGENT);
        asm volatile("s_waitcnt vmcnt(0)" ::: "memory");   // h stores at coherence point
        __syncthreads();
        if (tid == 0)
            __hip_atomic_store(&flags[blk * 32], (unsigned)(t + 2), __ATOMIC_RELAXED,
                               __HIP_MEMORY_SCOPE_AGENT);

        // off critical path: fp32 hs (+ final C) output
        {
            float4 o4; o4.x = hv[0]; o4.y = hv[1]; o4.z = hv[2]; o4.w = hv[3];
            *(float4*)(out + (size_t)t * BATCH * HID + b * HID + j0 + jh) = o4;
            if (t == T_STEPS - 1) {
                float4 c4; c4.x = cv[0]; c4.y = cv[1]; c4.z = cv[2]; c4.w = cv[3];
                *(float4*)(out + (size_t)T_STEPS * BATCH * HID + b * HID + j0 + jh) = c4;
            }
        }
        pb ^= 1;
    }
}

extern "C" void kernel_launch(void* const* d_in, const int* in_sizes, int n_in,
                              void* d_out, int out_size, void* d_ws, size_t ws_size,
                              hipStream_t stream) {
    (void)in_sizes; (void)n_in; (void)out_size; (void)ws_size;
    const float* x  = (const float*)d_in[0];
    const float* h0 = (const float*)d_in[1];
    const float* C0 = (const float*)d_in[2];
    const float* Wi = (const float*)d_in[3];
    const float* bi = (const float*)d_in[4];
    const float* Wf = (const float*)d_in[5];
    const float* bf = (const float*)d_in[6];
    const float* Wo = (const float*)d_in[7];
    const float* bo = (const float*)d_in[8];
    const float* Wg = (const float*)d_in[9];
    const float* bg = (const float*)d_in[10];
    float* out = (float*)d_out;

    char* ws = (char*)d_ws;
    unsigned*  flags = (unsigned*)ws;                                  // 16 KB region
    ushort_t*  hbuf  = (ushort_t*)(ws + 16384);                        // 256 KB
    ushort_t*  xb    = (ushort_t*)(ws + 16384 + 262144);               // 32 MB
    ushort_t*  wt    = (ushort_t*)(ws + 16384 + 262144 + 33554432);    // 12 MB

    hipMemsetAsync(flags, 0, 16384, stream);
    cvt_x<<<8192, 256, 0, stream>>>(x, xb, (T_STEPS * BATCH * DIN) / 8);
    xpose_w<<<dim3(24, 16, 4), 256, 0, stream>>>(Wi, Wf, Wo, Wg, wt);
    lstm_persist<<<NBLK, 256, 0, stream>>>(xb, wt, h0, C0, bi, bf, bo, bg, hbuf, flags, out);
}

// Round 6
// 4375.451 us; speedup vs baseline: 1.3797x; 1.0948x over previous
//
#include <hip/hip_runtime.h>
#include <hip/hip_bf16.h>
#include <stdint.h>

#define T_STEPS 512
#define BATCH   64
#define DIN     512
#define HID     1024
#define KDIM    1536        // HID + DIN (concat order: h then x)
#define NBLK    64          // persistent blocks
#define HPB     16          // hidden cols per block
#define GCPB    64          // gate cols per block = 4 gates * HPB
#define KGRPS   192         // KDIM / 8
#define XKG     64          // x-part kgrps (DIN/8)

typedef __bf16 bf16x8 __attribute__((ext_vector_type(8)));
typedef float  f32x4  __attribute__((ext_vector_type(4)));
typedef unsigned short ushort_t;
typedef unsigned long long u64_t;

__device__ __forceinline__ ushort_t f2bf(float f) {
    union { float f; unsigned u; } v; v.f = f;
    unsigned u = v.u;
    u += 0x7FFFu + ((u >> 16) & 1u);   // RNE
    return (ushort_t)(u >> 16);
}

__device__ __forceinline__ float fast_sig(float x) {
    return __builtin_amdgcn_rcpf(1.0f + __expf(-x));
}
__device__ __forceinline__ float fast_tanh(float x) {
    float e = __expf(2.0f * x);
    return 1.0f - 2.0f * __builtin_amdgcn_rcpf(e + 1.0f);
}

// ---------------- prep kernel 1: x fp32 -> bf16 ----------------
__global__ void cvt_x(const float* __restrict__ x, ushort_t* __restrict__ xb, int n8) {
    int i = blockIdx.x * blockDim.x + threadIdx.x;
    if (i >= n8) return;
    float4 v0 = ((const float4*)x)[2 * i];
    float4 v1 = ((const float4*)x)[2 * i + 1];
    uint4 o;
    o.x = (unsigned)f2bf(v0.x) | ((unsigned)f2bf(v0.y) << 16);
    o.y = (unsigned)f2bf(v0.z) | ((unsigned)f2bf(v0.w) << 16);
    o.z = (unsigned)f2bf(v1.x) | ((unsigned)f2bf(v1.y) << 16);
    o.w = (unsigned)f2bf(v1.z) | ((unsigned)f2bf(v1.w) << 16);
    ((uint4*)xb)[i] = o;
}

// ---------------- prep kernel 2: transpose W into per-block chunk-major bf16 ----------------
// wt[blk][kgrp][nn][8] bf16, blk = hidcol/HPB, nn = gate*HPB + hidcol%HPB, k = kgrp*8+j
__global__ void xpose_w(const float* __restrict__ Wi, const float* __restrict__ Wf,
                        const float* __restrict__ Wo, const float* __restrict__ Wg,
                        ushort_t* __restrict__ wt) {
    __shared__ float tile[64][65];
    int kt = blockIdx.x, nt = blockIdx.y, g = blockIdx.z;
    const float* W = (g == 0) ? Wi : (g == 1) ? Wf : (g == 2) ? Wo : Wg;
    int k0 = kt * 64, n0 = nt * 64;
    int c = threadIdx.x & 63, r0 = threadIdx.x >> 6;
#pragma unroll
    for (int i = 0; i < 16; ++i) {
        int r = r0 + i * 4;
        tile[r][c] = W[(size_t)(k0 + r) * HID + n0 + c];
    }
    __syncthreads();
#pragma unroll
    for (int p = 0; p < 2; ++p) {
        int q = threadIdx.x + p * 256;
        int n_inner = q & 7;
        int kgl = (q >> 3) & 7;
        int bl = q >> 6;
        int n = n0 + bl * 8 + n_inner;
        int blk = n >> 4;                 // HPB = 16
        int nn = g * HPB + (n & 15);
        int kgrp = (k0 >> 3) + kgl;
        __align__(16) ushort_t tmp[8];
#pragma unroll
        for (int j = 0; j < 8; ++j) tmp[j] = f2bf(tile[kgl * 8 + j][bl * 8 + n_inner]);
        *(uint4*)(wt + ((((size_t)blk * KGRPS + kgrp) * GCPB + nn) << 3)) = *(const uint4*)tmp;
    }
}

// ---------------- persistent LSTM kernel ----------------
// 64 blocks x 256 thr, 16 hidden cols each. Fine-grained sync:
//  - consumer wave w depends ONLY on producers [w*16, w*16+16) (its K-slice);
//    it polls those 16 flags, fences, loads, MFMAs — overlapping stragglers.
//  - producer release is per-wave: drain own h-stores -> atomicAdd(flag,+1);
//    consumers wait flag >= 4*(t+1). Only ONE full-block barrier (gbuf) on
//    the critical path; the gbuf-protection barrier sits after the flag-add.
__global__ __launch_bounds__(256, 1) void lstm_persist(
    const ushort_t* __restrict__ xbf,   // [T][B][DIN] bf16
    const ushort_t* __restrict__ wt,    // [NBLK][KGRPS][GCPB][8] bf16
    const float* __restrict__ h0, const float* __restrict__ C0,
    const float* __restrict__ b_i, const float* __restrict__ b_f,
    const float* __restrict__ b_o, const float* __restrict__ b_g,
    ushort_t* __restrict__ hbuf,        // [2][B][HID] bf16 double buffer
    unsigned* __restrict__ flags,       // [NBLK] at 32-uint (128B) spacing
    float* __restrict__ out)            // hs [T][B][HID] then C [B][HID]
{
    __shared__ __align__(16) ushort_t Wlx[XKG][GCPB][8];   // 64 KB x-part W
    __shared__ float gbuf[4][BATCH][GCPB + 2];             // 67.6 KB partials
    __shared__ float Cl[BATCH][HPB + 1];
    __shared__ float biasl[GCPB];

    const int tid  = threadIdx.x;
    const int blk  = blockIdx.x;
    const int wave = tid >> 6;
    const int lane = tid & 63;
    const int j0   = blk * HPB;
    const int m_lane = lane & 15;
    const int quad   = lane >> 4;
    const int koff   = quad * 8;

    const ushort_t* wblk = wt + (size_t)blk * KGRPS * GCPB * 8;

    // h-part W fragments -> registers: 8 chunks x 4 coltiles per wave (128 VGPR)
    bf16x8 wbh[8][4];
#pragma unroll
    for (int cc = 0; cc < 8; ++cc) {
        const int kgrp = (wave * 8 + cc) * 4 + quad;
#pragma unroll
        for (int ct = 0; ct < 4; ++ct)
            wbh[cc][ct] = *(const bf16x8*)(wblk + ((size_t)kgrp * GCPB + ct * 16 + m_lane) * 8);
    }
    // x-part W (kgrps 128..191) -> LDS
    {
        const uint4* src = (const uint4*)(wblk + (size_t)128 * GCPB * 8);
        uint4* dst = (uint4*)(&Wlx[0][0][0]);
        for (int i = tid; i < XKG * GCPB; i += 256) dst[i] = src[i];
    }

    if (tid < GCPB) {
        int g = tid >> 4, j = tid & 15;
        const float* bp = (g == 0) ? b_i : (g == 1) ? b_f : (g == 2) ? b_o : b_g;
        biasl[tid] = bp[j0 + j];
    }
    {
        int b = tid >> 2, jh = (tid & 3) * 4;
#pragma unroll
        for (int jj = 0; jj < 4; ++jj)
            Cl[b][jh + jj] = C0[b * HID + j0 + jh + jj];
        u64_t pk = 0;
#pragma unroll
        for (int jj = 0; jj < 4; ++jj)
            pk |= (u64_t)f2bf(h0[b * HID + j0 + jh + jj]) << (16 * jj);
        __hip_atomic_store((u64_t*)(hbuf + b * HID + j0 + jh), pk,
                           __ATOMIC_RELAXED, __HIP_MEMORY_SCOPE_AGENT);
    }
    asm volatile("s_waitcnt vmcnt(0)" ::: "memory");
    __syncthreads();
    if (tid == 0)   // flag semantics: value >= 4*(t+1)  <=>  h(t) fully visible
        __hip_atomic_store(&flags[blk * 32], 4u, __ATOMIC_RELAXED, __HIP_MEMORY_SCOPE_AGENT);

    int pb = 0;
    for (int t = 0; t < T_STEPS; ++t) {
        const ushort_t* xsrc = xbf + (size_t)t * BATCH * DIN;
        const ushort_t* hsrc = hbuf + pb * BATCH * HID;

        f32x4 acc[4][4];
#pragma unroll
        for (int rt = 0; rt < 4; ++rt)
#pragma unroll
            for (int ct = 0; ct < 4; ++ct)
                acc[rt][ct] = (f32x4){0.f, 0.f, 0.f, 0.f};

        // ---- x(t) loads before the spin: complete for free while waiting ----
        bf16x8 ax[4][4];
#pragma unroll
        for (int cc = 0; cc < 4; ++cc) {
            const ushort_t* ap = xsrc + (wave * 4 + cc) * 32 + koff;
#pragma unroll
            for (int rt = 0; rt < 4; ++rt)
                ax[cc][rt] = *(const bf16x8*)(ap + (size_t)(rt * 16 + m_lane) * DIN);
        }
        __builtin_amdgcn_sched_barrier(0);

        // ---- per-wave wait: only THIS wave's 16 producers ----
        // wave w consumes h cols [w*256, w*256+256) = blocks [w*16, w*16+16)
        if (lane < 16) {
            const unsigned* fp = &flags[(wave * 16 + lane) * 32];
            const unsigned need = 4u * (unsigned)(t + 1);
            while (__hip_atomic_load(fp, __ATOMIC_RELAXED, __HIP_MEMORY_SCOPE_AGENT) < need)
                __builtin_amdgcn_s_sleep(1);
        }
        __builtin_amdgcn_fence(__ATOMIC_ACQUIRE, "agent");   // per-wave acquire
        __builtin_amdgcn_sched_barrier(0);

        // ---- issue this wave's h loads (32 x 16B per lane) ----
        bf16x8 ah[8][4];
#pragma unroll
        for (int cc = 0; cc < 8; ++cc) {
            const ushort_t* ap = hsrc + (wave * 8 + cc) * 32 + koff;
#pragma unroll
            for (int rt = 0; rt < 4; ++rt)
                ah[cc][rt] = *(const bf16x8*)(ap + (size_t)(rt * 16 + m_lane) * HID);
        }
        __builtin_amdgcn_sched_barrier(0);

        // ---- x MFMAs (W from LDS): cover the h-load latency window ----
#pragma unroll
        for (int cc = 0; cc < 4; ++cc) {
            const int kgx = (wave * 4 + cc) * 4 + quad;
            bf16x8 bb[4];
#pragma unroll
            for (int ct = 0; ct < 4; ++ct)
                bb[ct] = *(const bf16x8*)(&Wlx[kgx][ct * 16 + m_lane][0]);
#pragma unroll
            for (int rt = 0; rt < 4; ++rt)
#pragma unroll
                for (int ct = 0; ct < 4; ++ct)
                    acc[rt][ct] = __builtin_amdgcn_mfma_f32_16x16x32_bf16(ax[cc][rt], bb[ct], acc[rt][ct], 0, 0, 0);
        }

        // ---- h MFMAs: A from just-landed regs, B resident in VGPRs ----
#pragma unroll
        for (int cc = 0; cc < 8; ++cc)
#pragma unroll
            for (int rt = 0; rt < 4; ++rt)
#pragma unroll
                for (int ct = 0; ct < 4; ++ct)
                    acc[rt][ct] = __builtin_amdgcn_mfma_f32_16x16x32_bf16(ah[cc][rt], wbh[cc][ct], acc[rt][ct], 0, 0, 0);

        // K-partials: D[row=(lane>>4)*4+r][col=lane&15]
#pragma unroll
        for (int rt = 0; rt < 4; ++rt)
#pragma unroll
            for (int ct = 0; ct < 4; ++ct)
#pragma unroll
                for (int r = 0; r < 4; ++r)
                    gbuf[wave][rt * 16 + quad * 4 + r][ct * 16 + m_lane] = acc[rt][ct][r];
        __syncthreads();   // ONLY critical-path barrier: cross-wave partials ready

        // pointwise: 256 threads, each owns (batch row b, 4 of 16 cols)
        float hv[4], cv[4];
        const int b = tid >> 2, jh = (tid & 3) * 4;
#pragma unroll
        for (int jj = 0; jj < 4; ++jj) {
            int j = jh + jj;
            float pre[4];
#pragma unroll
            for (int g = 0; g < 4; ++g) {
                int col = g * HPB + j;
                pre[g] = biasl[col] + gbuf[0][b][col] + gbuf[1][b][col]
                                    + gbuf[2][b][col] + gbuf[3][b][col];
            }
            float ig = fast_sig(pre[0]);
            float fg = fast_sig(pre[1]);
            float og = fast_sig(pre[2]);
            float gg = fast_tanh(pre[3]);
            float c_new = fg * Cl[b][jh + jj] + ig * gg;
            Cl[b][jh + jj] = c_new;
            cv[jj] = c_new;
            hv[jj] = og * fast_tanh(c_new);
        }
        u64_t pk = (u64_t)f2bf(hv[0]) | ((u64_t)f2bf(hv[1]) << 16)
                 | ((u64_t)f2bf(hv[2]) << 32) | ((u64_t)f2bf(hv[3]) << 48);
        __hip_atomic_store((u64_t*)(hbuf + (1 - pb) * BATCH * HID + b * HID + j0 + jh),
                           pk, __ATOMIC_RELAXED, __HIP_MEMORY_SCOPE_AGENT);
        // per-wave release: drain own h-stores, then bump this block's flag
        asm volatile("s_waitcnt vmcnt(0)" ::: "memory");
        if (lane == 0)
            __hip_atomic_fetch_add(&flags[blk * 32], 1u, __ATOMIC_RELAXED,
                                   __HIP_MEMORY_SCOPE_AGENT);

        // gbuf/Cl protection barrier — AFTER the release, off the inter-block path
        __syncthreads();

        // off critical path: fp32 hs (+ final C) output
        {
            float4 o4; o4.x = hv[0]; o4.y = hv[1]; o4.z = hv[2]; o4.w = hv[3];
            *(float4*)(out + (size_t)t * BATCH * HID + b * HID + j0 + jh) = o4;
            if (t == T_STEPS - 1) {
                float4 c4; c4.x = cv[0]; c4.y = cv[1]; c4.z = cv[2]; c4.w = cv[3];
                *(float4*)(out + (size_t)T_STEPS * BATCH * HID + b * HID + j0 + jh) = c4;
            }
        }
        pb ^= 1;
    }
}

extern "C" void kernel_launch(void* const* d_in, const int* in_sizes, int n_in,
                              void* d_out, int out_size, void* d_ws, size_t ws_size,
                              hipStream_t stream) {
    (void)in_sizes; (void)n_in; (void)out_size; (void)ws_size;
    const float* x  = (const float*)d_in[0];
    const float* h0 = (const float*)d_in[1];
    const float* C0 = (const float*)d_in[2];
    const float* Wi = (const float*)d_in[3];
    const float* bi = (const float*)d_in[4];
    const float* Wf = (const float*)d_in[5];
    const float* bf = (const float*)d_in[6];
    const float* Wo = (const float*)d_in[7];
    const float* bo = (const float*)d_in[8];
    const float* Wg = (const float*)d_in[9];
    const float* bg = (const float*)d_in[10];
    float* out = (float*)d_out;

    char* ws = (char*)d_ws;
    unsigned*  flags = (unsigned*)ws;                                  // 16 KB region
    ushort_t*  hbuf  = (ushort_t*)(ws + 16384);                        // 256 KB
    ushort_t*  xb    = (ushort_t*)(ws + 16384 + 262144);               // 32 MB
    ushort_t*  wt    = (ushort_t*)(ws + 16384 + 262144 + 33554432);    // 12 MB

    hipMemsetAsync(flags, 0, 16384, stream);
    cvt_x<<<8192, 256, 0, stream>>>(x, xb, (T_STEPS * BATCH * DIN) / 8);
    xpose_w<<<dim3(24, 16, 4), 256, 0, stream>>>(Wi, Wf, Wo, Wg, wt);
    lstm_persist<<<NBLK, 256, 0, stream>>>(xb, wt, h0, C0, bi, bf, bo, bg, hbuf, flags, out);
}